// Round 7
// baseline (64112.689 us; speedup 1.0000x reference)
//
#include <hip/hip_runtime.h>

// ContinuousGRULayer round 7: hybrid CU-resident weights, codegen-enforced.
//   128 WGs x 512 threads (8 waves -> 256-VGPR budget). Thread j owns neuron
//   j for ALL gates. Per gate (z,r,g): 12 K-slices in named registers made
//   opaque via asm (cannot be rematerialized as loads -- the round-4/6
//   failure), 6 slices in LDS (144 KB), 46 slices streamed from L2.
//   h/rh broadcast via LDS f16-packed; 2 barriers per RK4 stage eval.

namespace {
constexpr int kB = 128, kT = 512, kF = 128, kH = 512, kFH = 640;
// d_ws layout in uint4 (16B = 8 f16): slice p of neuron j at [region+p*kH+j]
constexpr int XS = (kF / 8) * kH;          // 8192 per x-gate
constexpr int HS = (kH / 8) * kH;          // 32768 per h-gate
constexpr int OXZ = 0, OXR = XS, OXG = 2 * XS;
constexpr int OHZ = 3 * XS, OHR = 3 * XS + HS, OHG = 3 * XS + 2 * HS;
constexpr int OTOT = 3 * XS + 3 * HS;      // 122880 * 16B = 1.97 MB
constexpr int NREG = 12;   // register-resident slices per gate (k = 0..11)
constexpr int NLDS = 6;    // LDS-resident slices per gate     (k = 12..17)
constexpr int RES = NREG + NLDS;           // streamed k = 18..63
}  // namespace

typedef _Float16 h2_t __attribute__((ext_vector_type(2)));

__device__ __forceinline__ unsigned short f2h(float f) {
  return __builtin_bit_cast(unsigned short, (_Float16)f);
}
__device__ __forceinline__ unsigned pack2h(float a, float b) {
  return (unsigned)f2h(a) | ((unsigned)f2h(b) << 16);
}
__device__ __forceinline__ float dot2(unsigned w, unsigned h, float acc) {
  return __builtin_amdgcn_fdot2(__builtin_bit_cast(h2_t, w),
                                __builtin_bit_cast(h2_t, h), acc, false);
}
__device__ __forceinline__ float dot2x4(uint4 w, uint4 h, float acc) {
  acc = dot2(w.x, h.x, acc); acc = dot2(w.y, h.y, acc);
  acc = dot2(w.z, h.z, acc); acc = dot2(w.w, h.w, acc);
  return acc;
}

// ---- weight pre-pack: f32 [H][F+H] -> f16 k8-transposed regions in d_ws ----
__global__ void convert_weights(const float* __restrict__ Wz,
                                const float* __restrict__ Wr,
                                const float* __restrict__ Wg,
                                uint4* __restrict__ ws) {
  int tid = blockIdx.x * 256 + threadIdx.x;
  if (tid >= OTOT) return;
  const float* W;
  int cbase, p, j;
  if (tid < 3 * XS) {
    int m = tid / XS, l = tid - m * XS;
    W = (m == 0) ? Wz : (m == 1) ? Wr : Wg;
    cbase = 0; p = l / kH; j = l - p * kH;
  } else {
    int t2 = tid - 3 * XS;
    int m = t2 / HS, l = t2 - m * HS;
    W = (m == 0) ? Wz : (m == 1) ? Wr : Wg;
    cbase = kF; p = l / kH; j = l - p * kH;
  }
  const float* s = W + (size_t)j * kFH + cbase + p * 8;
  uint4 o;
  o.x = pack2h(s[0], s[1]); o.y = pack2h(s[2], s[3]);
  o.z = pack2h(s[4], s[5]); o.w = pack2h(s[6], s[7]);
  ws[tid] = o;
}

// Load one resident slice into a named uint4 and make it asm-opaque so the
// compiler cannot turn it back into an in-loop load (round-4/6 failure mode).
#define DECL_OPQ(v, ptr, s)                                          \
  uint4 v = (ptr)[(s) * kH];                                         \
  asm volatile("" : "+v"(v.x), "+v"(v.y), "+v"(v.z), "+v"(v.w))

__global__ __launch_bounds__(512, 2) void cgru_res2(
    const float* __restrict__ x, const float* __restrict__ td,
    const float* __restrict__ bz, const float* __restrict__ br,
    const float* __restrict__ bg, const uint4* __restrict__ ws,
    float* __restrict__ out) {
  __shared__ __align__(16) uint4 WLz[NLDS][kH];    // 48 KB
  __shared__ __align__(16) uint4 WLr[NLDS][kH];    // 48 KB
  __shared__ __align__(16) uint4 WLg[NLDS][kH];    // 48 KB
  __shared__ __align__(16) unsigned hpk[kH / 2];   // stage h, f16 k-packed
  __shared__ __align__(16) unsigned rpk[kH / 2];   // r*h
  __shared__ __align__(16) unsigned xpk[kF / 2];   // x_t

  const int b = blockIdx.x;
  const int j = threadIdx.x;          // 0..511, owns neuron j (all gates)

  const uint4* __restrict__ wz = ws + OHZ + j;
  const uint4* __restrict__ wr = ws + OHR + j;
  const uint4* __restrict__ wg = ws + OHG + j;
  const uint4* __restrict__ wxz = ws + OXZ + j;
  const uint4* __restrict__ wxr = ws + OXR + j;
  const uint4* __restrict__ wxg = ws + OXG + j;

  // ---- register-resident slices (asm-opaque) ----
  DECL_OPQ(zw0, wz, 0);  DECL_OPQ(zw1, wz, 1);  DECL_OPQ(zw2, wz, 2);
  DECL_OPQ(zw3, wz, 3);  DECL_OPQ(zw4, wz, 4);  DECL_OPQ(zw5, wz, 5);
  DECL_OPQ(zw6, wz, 6);  DECL_OPQ(zw7, wz, 7);  DECL_OPQ(zw8, wz, 8);
  DECL_OPQ(zw9, wz, 9);  DECL_OPQ(zw10, wz, 10); DECL_OPQ(zw11, wz, 11);
  DECL_OPQ(rw0, wr, 0);  DECL_OPQ(rw1, wr, 1);  DECL_OPQ(rw2, wr, 2);
  DECL_OPQ(rw3, wr, 3);  DECL_OPQ(rw4, wr, 4);  DECL_OPQ(rw5, wr, 5);
  DECL_OPQ(rw6, wr, 6);  DECL_OPQ(rw7, wr, 7);  DECL_OPQ(rw8, wr, 8);
  DECL_OPQ(rw9, wr, 9);  DECL_OPQ(rw10, wr, 10); DECL_OPQ(rw11, wr, 11);
  DECL_OPQ(gw0, wg, 0);  DECL_OPQ(gw1, wg, 1);  DECL_OPQ(gw2, wg, 2);
  DECL_OPQ(gw3, wg, 3);  DECL_OPQ(gw4, wg, 4);  DECL_OPQ(gw5, wg, 5);
  DECL_OPQ(gw6, wg, 6);  DECL_OPQ(gw7, wg, 7);  DECL_OPQ(gw8, wg, 8);
  DECL_OPQ(gw9, wg, 9);  DECL_OPQ(gw10, wg, 10); DECL_OPQ(gw11, wg, 11);

  // ---- LDS-resident slices ----
  for (int q = j; q < NLDS * kH; q += 512) {
    const int s = q >> 9, jj = q & (kH - 1);
    WLz[s][jj] = (ws + OHZ)[(NREG + s) * kH + jj];
    WLr[s][jj] = (ws + OHR)[(NREG + s) * kH + jj];
    WLg[s][jj] = (ws + OHG)[(NREG + s) * kH + jj];
  }

  const float bzv = bz[j], brv = br[j], bgv = bg[j];
  float hb = 0.f, hs = 0.f, kacc = 0.f;
  if (j < kH / 2) hpk[j] = 0;        // h = 0

  for (int t = 0; t < kT; ++t) {
    if (j < kF / 2) {                // stage x_t, f16 k-packed
      const float2 xv =
          *(const float2*)(x + ((size_t)b * kT + t) * kF + 2 * j);
      xpk[j] = pack2h(xv.x, xv.y);
    }
    __syncthreads();                 // xpk (and initial hpk / prior h) visible

    // ---- x-part + bias, reused by all 8 RK4 evals of this timestep ----
    const uint4* xp4 = (const uint4*)xpk;
    float az = bzv, ar = brv, ag = bgv;
#pragma unroll 4
    for (int p = 0; p < kF / 8; ++p) {
      const uint4 xv = xp4[p];
      az = dot2x4(wxz[p * kH], xv, az);
      ar = dot2x4(wxr[p * kH], xv, ar);
      ag = dot2x4(wxg[p * kH], xv, ag);
    }
    const float dtv = fminf(td[(size_t)b * kT + t], 1.0f) * 0.5f;

    for (int e = 0; e < 8; ++e) {    // 2 ODE steps x 4 RK4 stages
      const int s = e & 3;
      const uint4* hp4 = (const uint4*)hpk;   // wave-uniform -> broadcast
      // ---- z dot ----
      float za = az;
      za = dot2x4(zw0, hp4[0], za);  za = dot2x4(zw1, hp4[1], za);
      za = dot2x4(zw2, hp4[2], za);  za = dot2x4(zw3, hp4[3], za);
      za = dot2x4(zw4, hp4[4], za);  za = dot2x4(zw5, hp4[5], za);
      za = dot2x4(zw6, hp4[6], za);  za = dot2x4(zw7, hp4[7], za);
      za = dot2x4(zw8, hp4[8], za);  za = dot2x4(zw9, hp4[9], za);
      za = dot2x4(zw10, hp4[10], za); za = dot2x4(zw11, hp4[11], za);
#pragma unroll
      for (int q = 0; q < NLDS; ++q)
        za = dot2x4(WLz[q][j], hp4[NREG + q], za);
#pragma unroll 4
      for (int k = RES; k < kH / 8; ++k)
        za = dot2x4(wz[k * kH], hp4[k], za);
      // ---- r dot ----
      float ra = ar;
      ra = dot2x4(rw0, hp4[0], ra);  ra = dot2x4(rw1, hp4[1], ra);
      ra = dot2x4(rw2, hp4[2], ra);  ra = dot2x4(rw3, hp4[3], ra);
      ra = dot2x4(rw4, hp4[4], ra);  ra = dot2x4(rw5, hp4[5], ra);
      ra = dot2x4(rw6, hp4[6], ra);  ra = dot2x4(rw7, hp4[7], ra);
      ra = dot2x4(rw8, hp4[8], ra);  ra = dot2x4(rw9, hp4[9], ra);
      ra = dot2x4(rw10, hp4[10], ra); ra = dot2x4(rw11, hp4[11], ra);
#pragma unroll
      for (int q = 0; q < NLDS; ++q)
        ra = dot2x4(WLr[q][j], hp4[NREG + q], ra);
#pragma unroll 4
      for (int k = RES; k < kH / 8; ++k)
        ra = dot2x4(wr[k * kH], hp4[k], ra);

      const float z = 1.0f / (1.0f + __expf(-za));
      const float r = 1.0f / (1.0f + __expf(-ra));
      ((unsigned short*)rpk)[j] = f2h(r * hs);
      __syncthreads();               // #1: rh visible; hpk reads done

      // ---- g dot over rh ----
      const uint4* rp4 = (const uint4*)rpk;
      float ga = ag;
      ga = dot2x4(gw0, rp4[0], ga);  ga = dot2x4(gw1, rp4[1], ga);
      ga = dot2x4(gw2, rp4[2], ga);  ga = dot2x4(gw3, rp4[3], ga);
      ga = dot2x4(gw4, rp4[4], ga);  ga = dot2x4(gw5, rp4[5], ga);
      ga = dot2x4(gw6, rp4[6], ga);  ga = dot2x4(gw7, rp4[7], ga);
      ga = dot2x4(gw8, rp4[8], ga);  ga = dot2x4(gw9, rp4[9], ga);
      ga = dot2x4(gw10, rp4[10], ga); ga = dot2x4(gw11, rp4[11], ga);
#pragma unroll
      for (int q = 0; q < NLDS; ++q)
        ga = dot2x4(WLg[q][j], rp4[NREG + q], ga);
#pragma unroll 4
      for (int k = RES; k < kH / 8; ++k)
        ga = dot2x4(wg[k * kH], rp4[k], ga);

      const float g = tanhf(ga);
      const float kk = (1.0f - z) * (g - hs);
      kacc = (s == 0) ? kk : kacc + ((s == 3) ? 1.0f : 2.0f) * kk;
      float nxt;
      if (s < 3) {
        nxt = fmaf((s == 2 ? 1.0f : 0.5f) * dtv, kk, hb);
      } else {
        hb = fmaf(dtv * (1.0f / 6.0f), kacc, hb);
        nxt = hb;
      }
      ((unsigned short*)hpk)[j] = f2h(nxt);
      hs = nxt;
      __syncthreads();               // #2: new h visible
    }

    out[((size_t)b * kT + t) * kH + j] = hb;  // coalesced f32
  }
}

extern "C" void kernel_launch(void* const* d_in, const int* in_sizes, int n_in,
                              void* d_out, int out_size, void* d_ws, size_t ws_size,
                              hipStream_t stream) {
  const float* x  = (const float*)d_in[0];
  const float* td = (const float*)d_in[1];
  const float* Wz = (const float*)d_in[2];
  const float* bz = (const float*)d_in[3];
  const float* Wr = (const float*)d_in[4];
  const float* br = (const float*)d_in[5];
  const float* Wg = (const float*)d_in[6];
  const float* bg = (const float*)d_in[7];
  float* out = (float*)d_out;

  convert_weights<<<(OTOT + 255) / 256, 256, 0, stream>>>(
      Wz, Wr, Wg, (uint4*)d_ws);
  cgru_res2<<<kB, 512, 0, stream>>>(
      x, td, bz, br, bg, (const uint4*)d_ws, out);
}

// Round 8
// 28159.091 us; speedup vs baseline: 2.2768x; 2.2768x over previous
//
#include <hip/hip_runtime.h>

// ContinuousGRULayer round 8: i8 recurrent weights (per-row scale) streamed at
// half the bytes, h/rh in exact 2-level i8 fixed point (two v_dot4_i32_i8 per
// weight u32 -> integer-exact h, ~7-bit weights). Round-2 shell: 128 WGs x
// 1024 threads, gate-split (half0: z + g-lowK + RK4 commit; half1: r + rh +
// g-highK), 3 barriers/eval. Residency: 18 slices LDS (144 KB) + 8 slices
// reg (asm-opaque, r7-proven). x-part stays f16 dot2, amortized per timestep.

namespace {
constexpr int kB = 128, kT = 512, kF = 128, kH = 512, kFH = 640;
// uint4-unit offsets in d_ws
constexpr int QZ4 = 0, QR4 = 16384, QG4 = 32768;        // i8 recurrent, 32 slices/gate
constexpr int WXZ4 = 49152, WXR4 = 57344, WXG4 = 65536; // f16 x-part, 16 slices/gate
constexpr size_t CS_OFF = (size_t)73728 * 16;           // 3*512 f32 scales
constexpr float HSCL = 8128.0f;                         // h fixed-point scale (clip 2)
}  // namespace

typedef _Float16 h2_t __attribute__((ext_vector_type(2)));

__device__ __forceinline__ unsigned short f2h(float f) {
  return __builtin_bit_cast(unsigned short, (_Float16)f);
}
__device__ __forceinline__ unsigned pack2h(float a, float b) {
  return (unsigned)f2h(a) | ((unsigned)f2h(b) << 16);
}
__device__ __forceinline__ float dot2(unsigned w, unsigned h, float acc) {
  return __builtin_amdgcn_fdot2(__builtin_bit_cast(h2_t, w),
                                __builtin_bit_cast(h2_t, h), acc, false);
}
__device__ __forceinline__ float dot2x4(uint4 w, uint4 h, float acc) {
  acc = dot2(w.x, h.x, acc); acc = dot2(w.y, h.y, acc);
  acc = dot2(w.z, h.z, acc); acc = dot2(w.w, h.w, acc);
  return acc;
}
__device__ __forceinline__ uint4 pk8(const float* s) {
  const float4 a = *(const float4*)s;
  const float4 b = *(const float4*)(s + 4);
  uint4 o;
  o.x = pack2h(a.x, a.y); o.y = pack2h(a.z, a.w);
  o.z = pack2h(b.x, b.y); o.w = pack2h(b.z, b.w);
  return o;
}
__device__ __forceinline__ int sd4(unsigned a, unsigned b, int acc) {
  return __builtin_amdgcn_sdot4((int)a, (int)b, acc, false);
}
// one 16-weight i8 slice (uint4) against h hi/lo fixed-point arrays
__device__ __forceinline__ void dslice(const uint4 w, const unsigned* hh,
                                       const unsigned* hl, int p,
                                       int& ah, int& al) {
  ah = sd4(w.x, hh[4 * p + 0], ah); al = sd4(w.x, hl[4 * p + 0], al);
  ah = sd4(w.y, hh[4 * p + 1], ah); al = sd4(w.y, hl[4 * p + 1], al);
  ah = sd4(w.z, hh[4 * p + 2], ah); al = sd4(w.z, hl[4 * p + 2], al);
  ah = sd4(w.w, hh[4 * p + 3], ah); al = sd4(w.w, hl[4 * p + 3], al);
}

#define DECL_OPQ(v, ptr, s)                                          \
  uint4 v = (ptr)[(s) * kH];                                         \
  asm volatile("" : "+v"(v.x), "+v"(v.y), "+v"(v.z), "+v"(v.w))

// ---- pre-pack: i8 recurrent (per-row scale) + f16 x-part + scales ----
__global__ void quant_weights(const float* __restrict__ Wz,
                              const float* __restrict__ Wr,
                              const float* __restrict__ Wg,
                              void* __restrict__ ws) {
  const int bx = blockIdx.x;            // 0..1535 = gate*512 + j
  const int gate = bx >> 9, j = bx & 511;
  const float* W = (gate == 0) ? Wz : (gate == 1) ? Wr : Wg;
  const float* row = W + (size_t)j * kFH;
  const int lane = threadIdx.x;         // 0..63, owns recurrent cols 8l..8l+7
  uint4* ws4 = (uint4*)ws;

  const float* src = row + kF + lane * 8;
  float v[8]; float m = 0.f;
#pragma unroll
  for (int i = 0; i < 8; ++i) { v[i] = src[i]; m = fmaxf(m, fabsf(v[i])); }
#pragma unroll
  for (int off = 32; off; off >>= 1) m = fmaxf(m, __shfl_xor(m, off));
  const float inv = 127.f / m;
  unsigned u0 = 0, u1 = 0;
#pragma unroll
  for (int i = 0; i < 4; ++i) {
    int q = __float2int_rn(v[i] * inv); q = max(-127, min(127, q));
    u0 |= ((unsigned)(q & 255)) << (8 * i);
  }
#pragma unroll
  for (int i = 0; i < 4; ++i) {
    int q = __float2int_rn(v[4 + i] * inv); q = max(-127, min(127, q));
    u1 |= ((unsigned)(q & 255)) << (8 * i);
  }
  const int p = lane >> 1, sub = lane & 1;
  const int qbase = (gate == 0) ? QZ4 : (gate == 1) ? QR4 : QG4;
  *(uint2*)((char*)ws + ((size_t)(qbase + p * kH + j)) * 16 + sub * 8) =
      make_uint2(u0, u1);
  if (lane < 16) {
    const int xbase = (gate == 0) ? WXZ4 : (gate == 1) ? WXR4 : WXG4;
    ws4[xbase + lane * kH + j] = pk8(row + lane * 8);
  }
  if (lane == 0)
    ((float*)((char*)ws + CS_OFF))[gate * 512 + j] = m / (127.f * HSCL);
}

__global__ __launch_bounds__(1024, 4) void cgru_i8(
    const float* __restrict__ x, const float* __restrict__ td,
    const float* __restrict__ bz, const float* __restrict__ br,
    const float* __restrict__ bg, const uint4* __restrict__ ws,
    float* __restrict__ out) {
  __shared__ uint4 WLa[2][6][kH];      // z|r slices 8..13      98,304 B
  __shared__ uint4 WLg[2][3][kH];      // g slices {0..2|16..18} 49,152 B
  __shared__ unsigned hh[kH / 4], hl[kH / 4];      // h hi/lo i8 (512 B each)
  __shared__ unsigned rhh[kH / 4], rhl[kH / 4];    // r*h hi/lo
  __shared__ unsigned xpk[kF / 2];                 // x_t f16-packed
  __shared__ float gpart[kH];                      // half1's g partial

  const int b = blockIdx.x;
  const int tid = threadIdx.x;
  const int j = tid & (kH - 1);
  const int half = tid >> 9;

  const uint4* __restrict__ wQa = ws + (half ? QR4 : QZ4) + j;
  const uint4* __restrict__ wQg = ws + QG4 + j;
  const uint4* __restrict__ wxa = ws + (half ? WXR4 : WXZ4) + j;
  const uint4* __restrict__ wxg = ws + WXG4 + j;
  const float* cs = (const float*)((const char*)ws + CS_OFF);
  const float csa = cs[(half ? 512 : 0) + j];
  const float csg = cs[1024 + j];

  // ---- reg-resident A-gate slices 0..7 (asm-opaque; r7-proven to stick) ----
  DECL_OPQ(a0, wQa, 0); DECL_OPQ(a1, wQa, 1); DECL_OPQ(a2, wQa, 2);
  DECL_OPQ(a3, wQa, 3); DECL_OPQ(a4, wQa, 4); DECL_OPQ(a5, wQa, 5);
  DECL_OPQ(a6, wQa, 6); DECL_OPQ(a7, wQa, 7);
  // ---- LDS-resident slices ----
  {
    const uint4* qa = ws + (half ? QR4 : QZ4);
#pragma unroll
    for (int q = 0; q < 6; ++q) WLa[half][q][j] = qa[(8 + q) * kH + j];
#pragma unroll
    for (int q = 0; q < 3; ++q)
      WLg[half][q][j] = (ws + QG4)[((half ? 16 : 0) + q) * kH + j];
  }

  const float ba = half ? br[j] : bz[j];
  const float bgv = bg[j];
  float hb = 0.f, hs = 0.f, kacc = 0.f, zv = 0.f, dtv = 0.f;
  if (tid < kH / 4) { hh[tid] = 0; hl[tid] = 0; }   // h = 0

  for (int t = 0; t < kT; ++t) {
    if (tid < kF / 2) {   // stage x_t f16-packed
      const float2 xv =
          *(const float2*)(x + ((size_t)b * kT + t) * kF + 2 * tid);
      xpk[tid] = pack2h(xv.x, xv.y);
    }
    __syncthreads();      // xpk (+ init h, + LDS weights on t=0) visible

    // ---- x-part + bias, reused across all 8 RK4 evals ----
    const uint4* xp4 = (const uint4*)xpk;
    float ax = ba;
#pragma unroll 4
    for (int p = 0; p < 16; ++p) ax = dot2x4(wxa[p * kH], xp4[p], ax);
    float agx = half ? 0.f : bgv;
#pragma unroll 4
    for (int p = 0; p < 8; ++p)
      agx = dot2x4(wxg[(half * 8 + p) * kH], xp4[half * 8 + p], agx);
    if (half == 0) dtv = fminf(td[(size_t)b * kT + t], 1.0f) * 0.5f;

    for (int e = 0; e < 8; ++e) {   // 2 ODE steps x 4 RK4 stages
      const int s = e & 3;
      // ---- A dot (z or r): 8 reg + 6 LDS + 18 streamed slices ----
      int ah = 0, al = 0;
      dslice(a0, hh, hl, 0, ah, al); dslice(a1, hh, hl, 1, ah, al);
      dslice(a2, hh, hl, 2, ah, al); dslice(a3, hh, hl, 3, ah, al);
      dslice(a4, hh, hl, 4, ah, al); dslice(a5, hh, hl, 5, ah, al);
      dslice(a6, hh, hl, 6, ah, al); dslice(a7, hh, hl, 7, ah, al);
#pragma unroll
      for (int q = 0; q < 6; ++q)
        dslice(WLa[half][q][j], hh, hl, 8 + q, ah, al);
#pragma unroll 6
      for (int p = 14; p < 32; ++p)
        dslice(wQa[p * kH], hh, hl, p, ah, al);
      const float aA = ax + csa * fmaf(128.f, (float)ah, (float)al);

      if (half == 0) {
        zv = 1.0f / (1.0f + __expf(-aA));
      } else {
        const float r = 1.0f / (1.0f + __expf(-aA));
        const int q15 = (int)((const char*)hh)[j] * 128 +
                        (int)((const char*)hl)[j];
        const float hv = (float)q15 * (1.0f / HSCL);
        int q = __float2int_rn(fminf(fmaxf(r * hv, -2.f), 2.f) * HSCL);
        const int hi = (q + 64) >> 7, lo = q - (hi << 7);
        ((char*)rhh)[j] = (char)hi; ((char*)rhl)[j] = (char)lo;
      }
      __syncthreads();   // #1: rh visible; h reads done

      // ---- G dot over rh: 3 LDS + 13 streamed (own K-half) ----
      int gh = 0, gl = 0;
      const int bs = half << 4;
#pragma unroll
      for (int q = 0; q < 3; ++q)
        dslice(WLg[half][q][j], rhh, rhl, bs + q, gh, gl);
#pragma unroll 4
      for (int p = bs + 3; p < bs + 16; ++p)
        dslice(wQg[p * kH], rhh, rhl, p, gh, gl);
      const float gp = agx + csg * fmaf(128.f, (float)gh, (float)gl);
      if (half == 1) gpart[j] = gp;
      __syncthreads();   // #2: gpart visible; rh reads done

      if (half == 0) {
        const float g = tanhf(gp + gpart[j]);
        const float kk = (1.0f - zv) * (g - hs);
        kacc = (s == 0) ? kk : kacc + ((s == 3) ? 1.0f : 2.0f) * kk;
        float nxt;
        if (s < 3) {
          nxt = fmaf((s == 2 ? 1.0f : 0.5f) * dtv, kk, hb);
        } else {
          hb = fmaf(dtv * (1.0f / 6.0f), kacc, hb);
          nxt = hb;
        }
        hs = nxt;
        int q = __float2int_rn(fminf(fmaxf(nxt, -2.f), 2.f) * HSCL);
        const int hi = (q + 64) >> 7, lo = q - (hi << 7);
        ((char*)hh)[j] = (char)hi; ((char*)hl)[j] = (char)lo;
      }
      __syncthreads();   // #3: new h visible
    }

    if (half == 0) out[((size_t)b * kT + t) * kH + j] = hb;  // coalesced
  }
}

extern "C" void kernel_launch(void* const* d_in, const int* in_sizes, int n_in,
                              void* d_out, int out_size, void* d_ws, size_t ws_size,
                              hipStream_t stream) {
  const float* x  = (const float*)d_in[0];
  const float* td = (const float*)d_in[1];
  const float* Wz = (const float*)d_in[2];
  const float* bz = (const float*)d_in[3];
  const float* Wr = (const float*)d_in[4];
  const float* br = (const float*)d_in[5];
  const float* Wg = (const float*)d_in[6];
  const float* bg = (const float*)d_in[7];
  float* out = (float*)d_out;

  quant_weights<<<3 * kH, 64, 0, stream>>>(Wz, Wr, Wg, d_ws);
  cgru_i8<<<kB, 1024, 0, stream>>>(
      x, td, bz, br, bg, (const uint4*)d_ws, out);
}